// Round 2
// baseline (248.133 us; speedup 1.0000x reference)
//
#include <hip/hip_runtime.h>

// Softmax over 32M fp32: out = exp(x) / sum(exp(x))  (no max-subtraction, per reference)
//
// Two-pass, memory-bound (REVERTED from cooperative fusion: hipLaunchCooperativeKernel
// + grid.sync() hung the MI355X container twice — likely rocprof replay launching the
// cooperative kernel without cooperative semantics. Do not retry without new info.)
//
//   Pass 1: grid-stride float4 loads (x4 ILP), per-thread exp-sum, wave64 shuffle
//           reduce, LDS reduce, per-block partial -> partials[blockIdx]
//           (own-slot writes: no atomics, no workspace init required).
//   Pass 2: each block re-reduces the 2048 partials (8 KB, L2/L3-hot), then
//           grid-stride float4 exp+scale (x4 ILP) with non-temporal stores
//           (keeps the input resident in L3 for the duration of the pass).

#define BLOCK 256
#define GRID 2048  // 2048 blocks x 4 waves = 8192 waves = exactly full residency

// clang-native vector type: __builtin_nontemporal_store requires it
// (HIP's float4 is a class and is rejected).
typedef float vfloat4 __attribute__((ext_vector_type(4)));

__global__ __launch_bounds__(BLOCK) void softmax_reduce(
    const float* __restrict__ inp, float* __restrict__ partials, int n4) {
  const vfloat4* __restrict__ in4 = (const vfloat4*)inp;
  const int tid = blockIdx.x * BLOCK + threadIdx.x;
  const int stride = gridDim.x * BLOCK;

  // x4 ILP: four independent loads in flight per thread.
  // n4 = 8M, stride = 512K -> exactly 4 main-loop iterations, no tail.
  float s0 = 0.0f, s1 = 0.0f, s2 = 0.0f, s3 = 0.0f;
  int i = tid;
  for (; i + 3 * stride < n4; i += 4 * stride) {
    vfloat4 a = in4[i];
    vfloat4 b = in4[i + stride];
    vfloat4 c = in4[i + 2 * stride];
    vfloat4 d = in4[i + 3 * stride];
    s0 += __expf(a.x) + __expf(a.y) + __expf(a.z) + __expf(a.w);
    s1 += __expf(b.x) + __expf(b.y) + __expf(b.z) + __expf(b.w);
    s2 += __expf(c.x) + __expf(c.y) + __expf(c.z) + __expf(c.w);
    s3 += __expf(d.x) + __expf(d.y) + __expf(d.z) + __expf(d.w);
  }
  for (; i < n4; i += stride) {
    vfloat4 a = in4[i];
    s0 += __expf(a.x) + __expf(a.y) + __expf(a.z) + __expf(a.w);
  }
  float s = (s0 + s1) + (s2 + s3);

  #pragma unroll
  for (int off = 32; off > 0; off >>= 1)
    s += __shfl_down(s, off, 64);

  __shared__ float wsum[BLOCK / 64];
  if ((threadIdx.x & 63) == 0) wsum[threadIdx.x >> 6] = s;
  __syncthreads();
  if (threadIdx.x == 0)
    partials[blockIdx.x] = wsum[0] + wsum[1] + wsum[2] + wsum[3];
}

__global__ __launch_bounds__(BLOCK) void softmax_scale(
    const float* __restrict__ inp, float* __restrict__ out,
    const float* __restrict__ partials, int n4) {
  // Every block independently reduces the GRID partials (8 KB, cache-hot).
  float t = 0.0f;
  #pragma unroll
  for (int k = 0; k < GRID / BLOCK; ++k)
    t += partials[k * BLOCK + threadIdx.x];

  #pragma unroll
  for (int off = 32; off > 0; off >>= 1)
    t += __shfl_down(t, off, 64);

  __shared__ float wsum[BLOCK / 64];
  if ((threadIdx.x & 63) == 0) wsum[threadIdx.x >> 6] = t;
  __syncthreads();
  const float r = 1.0f / (wsum[0] + wsum[1] + wsum[2] + wsum[3]);

  const vfloat4* __restrict__ in4 = (const vfloat4*)inp;
  vfloat4* __restrict__ out4 = (vfloat4*)out;
  const int tid = blockIdx.x * BLOCK + threadIdx.x;
  const int stride = gridDim.x * BLOCK;

  int i = tid;
  for (; i + 3 * stride < n4; i += 4 * stride) {
    vfloat4 a = in4[i];
    vfloat4 b = in4[i + stride];
    vfloat4 c = in4[i + 2 * stride];
    vfloat4 d = in4[i + 3 * stride];
    vfloat4 oa, ob, oc, od;
    oa.x = __expf(a.x) * r; oa.y = __expf(a.y) * r;
    oa.z = __expf(a.z) * r; oa.w = __expf(a.w) * r;
    ob.x = __expf(b.x) * r; ob.y = __expf(b.y) * r;
    ob.z = __expf(b.z) * r; ob.w = __expf(b.w) * r;
    oc.x = __expf(c.x) * r; oc.y = __expf(c.y) * r;
    oc.z = __expf(c.z) * r; oc.w = __expf(c.w) * r;
    od.x = __expf(d.x) * r; od.y = __expf(d.y) * r;
    od.z = __expf(d.z) * r; od.w = __expf(d.w) * r;
    __builtin_nontemporal_store(oa, &out4[i]);
    __builtin_nontemporal_store(ob, &out4[i + stride]);
    __builtin_nontemporal_store(oc, &out4[i + 2 * stride]);
    __builtin_nontemporal_store(od, &out4[i + 3 * stride]);
  }
  for (; i < n4; i += stride) {
    vfloat4 a = in4[i];
    vfloat4 oa;
    oa.x = __expf(a.x) * r; oa.y = __expf(a.y) * r;
    oa.z = __expf(a.z) * r; oa.w = __expf(a.w) * r;
    __builtin_nontemporal_store(oa, &out4[i]);
  }
}

extern "C" void kernel_launch(void* const* d_in, const int* in_sizes, int n_in,
                              void* d_out, int out_size, void* d_ws, size_t ws_size,
                              hipStream_t stream) {
  const float* inp = (const float*)d_in[0];
  float* out = (float*)d_out;
  float* partials = (float*)d_ws;  // GRID floats (8 KB) of workspace
  int n = in_sizes[0];
  int n4 = n >> 2;  // N = 2^25, divisible by 4

  softmax_reduce<<<GRID, BLOCK, 0, stream>>>(inp, partials, n4);
  softmax_scale<<<GRID, BLOCK, 0, stream>>>(inp, out, partials, n4);
}